// Round 1
// baseline (88.326 us; speedup 1.0000x reference)
//
#include <hip/hip_runtime.h>
#include <hip/hip_fp16.h>

#define IN_F 4096
#define OUT_F 11008
#define FP_F 256
#define NROWS 512
#define BN 64

typedef int v4i __attribute__((ext_vector_type(4)));
typedef float v4f __attribute__((ext_vector_type(4)));
typedef _Float16 half8 __attribute__((ext_vector_type(8)));

__device__ __forceinline__ int pack4(v4i a) {
  return (int)((unsigned)(a[0] & 255) | ((unsigned)(a[1] & 255) << 8) |
               ((unsigned)(a[2] & 255) << 16) | ((unsigned)(a[3] & 255) << 24));
}

// One block per row m. Quantize x row to int8 (outlier cols zeroed), store in
// MFMA-fragment-order layout: chunk (mg, kb) of 16 rows x 64 k; within chunk,
// lane = (m&15) + 16*((k>>4)&3), byte = k&15.
__global__ __launch_bounds__(256) void quant_kernel(
    const float* __restrict__ x, const int* __restrict__ ind,
    signed char* __restrict__ qx, _Float16* __restrict__ act,
    float* __restrict__ xscale)
{
  const int m = blockIdx.x;
  const int t = threadIdx.x;
  __shared__ unsigned char zm[IN_F];
  __shared__ float wmax[4];
  int* zmi = (int*)zm;
  #pragma unroll
  for (int i = 0; i < IN_F / 4 / 256; ++i) zmi[t + i * 256] = 0;
  __syncthreads();
  const int idx = ind[t];
  zm[idx] = 1;  // duplicate ind writes same value: benign
  __syncthreads();

  const float* xr = x + (size_t)m * IN_F;
  float v[16];
  float amax = 0.f;
  const int k0 = t * 16;
  #pragma unroll
  for (int q = 0; q < 4; ++q) {
    v4f f = *(const v4f*)(xr + k0 + q * 4);
    #pragma unroll
    for (int j = 0; j < 4; ++j) {
      float mv = zm[k0 + q * 4 + j] ? 0.f : f[j];
      v[q * 4 + j] = mv;
      amax = fmaxf(amax, fabsf(mv));
    }
  }
  #pragma unroll
  for (int off = 32; off >= 1; off >>= 1)
    amax = fmaxf(amax, __shfl_xor(amax, off));
  if ((t & 63) == 0) wmax[t >> 6] = amax;
  __syncthreads();
  amax = fmaxf(fmaxf(wmax[0], wmax[1]), fmaxf(wmax[2], wmax[3]));
  const float scale = fmaxf(amax / 127.0f, 1e-8f);
  if (t == 0) xscale[m] = scale;
  const float inv = 1.0f / scale;

  union { signed char b[16]; v4i w4; } pk;
  #pragma unroll
  for (int j = 0; j < 16; ++j) {
    float qv = rintf(v[j] * inv);            // round-half-even, like jnp.round
    qv = fminf(fmaxf(qv, -128.f), 127.f);
    pk.b[j] = (signed char)qv;
  }
  const int mg = m >> 4;
  const int kb = t >> 2;
  const int lane = (m & 15) + 16 * (t & 3);
  ((v4i*)qx)[(mg * 64 + kb) * 64 + lane] = pk.w4;

  // outlier activations (original, un-zeroed values), f16
  act[m * FP_F + t] = (_Float16)xr[idx];
}

// BM=512 (all rows), BN=64, BK=64. 8 waves; wave w owns rows [w*64, w*64+64).
// A fragments read directly from global (L2-resident fragment-order q_x).
// B (q_weight int32) register-prefetched 2 steps ahead, packed to int8 in a
// 2 x 4KB LDS double buffer laid out in fragment order.
__global__ __launch_bounds__(512) void gemm_kernel(
    const signed char* __restrict__ qx, const int* __restrict__ qw,
    const float* __restrict__ scol, const float* __restrict__ wc,
    const float* __restrict__ bias, const _Float16* __restrict__ act,
    const float* __restrict__ xscale, float* __restrict__ out)
{
  __shared__ __align__(16) signed char blds[2][4096];
  const int tid = threadIdx.x;
  const int w = tid >> 6;
  const int l = tid & 63;
  const int n0 = blockIdx.x * BN;

  // B staging mapping: thread -> chunk c (n-group), frag-lane sl, 8-byte half h
  const int c = tid >> 7;
  const int sl = (tid >> 1) & 63;
  const int h = tid & 1;
  const int brow = n0 + c * 16 + (sl & 15);
  const int* bsrc = qw + (size_t)brow * IN_F + ((sl >> 4) * 16 + h * 8);
  signed char* bdst = &blds[0][0] + (c * 1024 + sl * 16 + h * 8);

  v4i br[2][2];
  br[0][0] = *(const v4i*)(bsrc + 0);
  br[0][1] = *(const v4i*)(bsrc + 4);
  br[1][0] = *(const v4i*)(bsrc + 64);
  br[1][1] = *(const v4i*)(bsrc + 68);

  v4i acc[4][4] = {};

  { // stage B(0) into buffer 0
    int2 d;
    d.x = pack4(br[0][0]);
    d.y = pack4(br[0][1]);
    *(int2*)(bdst) = d;
  }
  __syncthreads();

  const v4i* qx4 = (const v4i*)qx;
  const int aBase = (w * 4) * 4096 + l;

#define K_STEP(T, CUR) do {                                                   \
    const int t_ = (T);                                                       \
    v4i a[4];                                                                 \
    _Pragma("unroll")                                                         \
    for (int mf = 0; mf < 4; ++mf)                                            \
      a[mf] = qx4[aBase + mf * 4096 + t_ * 64];                               \
    if (t_ + 1 < 64) {                                                        \
      int2 d;                                                                 \
      d.x = pack4(br[(CUR) ^ 1][0]);                                          \
      d.y = pack4(br[(CUR) ^ 1][1]);                                          \
      *(int2*)(bdst + ((CUR) ^ 1) * 4096) = d;                                \
    }                                                                         \
    if (t_ + 2 < 64) {                                                        \
      const int* s_ = bsrc + (t_ + 2) * 64;                                   \
      br[CUR][0] = *(const v4i*)(s_);                                         \
      br[CUR][1] = *(const v4i*)(s_ + 4);                                     \
    }                                                                         \
    const signed char* rb = &blds[CUR][0];                                    \
    v4i b[4];                                                                 \
    _Pragma("unroll")                                                         \
    for (int nf = 0; nf < 4; ++nf)                                            \
      b[nf] = *(const v4i*)(rb + nf * 1024 + l * 16);                         \
    _Pragma("unroll")                                                         \
    for (int mf = 0; mf < 4; ++mf)                                            \
      _Pragma("unroll")                                                       \
      for (int nf = 0; nf < 4; ++nf)                                          \
        acc[mf][nf] = __builtin_amdgcn_mfma_i32_16x16x64_i8(                  \
            a[mf], b[nf], acc[mf][nf], 0, 0, 0);                              \
    __syncthreads();                                                          \
  } while (0)

  for (int t2 = 0; t2 < 64; t2 += 2) {
    K_STEP(t2, 0);
    K_STEP(t2 + 1, 1);
  }
#undef K_STEP

  // epilogue scales
  float sc[4], bs[4];
  #pragma unroll
  for (int nf = 0; nf < 4; ++nf) {
    sc[nf] = scol[n0 + nf * 16 + (l & 15)];
    bs[nf] = bias[n0 + nf * 16 + (l & 15)];
  }
  float xs[4][4];
  #pragma unroll
  for (int mf = 0; mf < 4; ++mf)
    #pragma unroll
    for (int j = 0; j < 4; ++j)
      xs[mf][j] = xscale[w * 64 + mf * 16 + (l >> 4) * 4 + j];

  v4f facc[4][4];
  #pragma unroll
  for (int mf = 0; mf < 4; ++mf)
    #pragma unroll
    for (int nf = 0; nf < 4; ++nf)
      #pragma unroll
      for (int j = 0; j < 4; ++j)
        facc[mf][nf][j] = (float)acc[mf][nf][j] * xs[mf][j] * sc[nf];

  // outlier fp phase: K=256 in 8 steps of 32, f16 MFMA into same f32 acc
  #pragma unroll
  for (int ks = 0; ks < 8; ++ks) {
    const int kk = ks * 32 + (l >> 4) * 8;
    half8 ah[4];
    #pragma unroll
    for (int mf = 0; mf < 4; ++mf) {
      const int row = w * 64 + mf * 16 + (l & 15);
      ah[mf] = *(const half8*)(act + row * FP_F + kk);
    }
    half8 bh[4];
    #pragma unroll
    for (int nf = 0; nf < 4; ++nf) {
      const float* wr = wc + (size_t)(n0 + nf * 16 + (l & 15)) * FP_F + kk;
      v4f w0 = *(const v4f*)(wr);
      v4f w1 = *(const v4f*)(wr + 4);
      half8 hb;
      #pragma unroll
      for (int j = 0; j < 4; ++j) {
        hb[j] = (_Float16)w0[j];
        hb[4 + j] = (_Float16)w1[j];
      }
      bh[nf] = hb;
    }
    #pragma unroll
    for (int mf = 0; mf < 4; ++mf)
      #pragma unroll
      for (int nf = 0; nf < 4; ++nf)
        facc[mf][nf] = __builtin_amdgcn_mfma_f32_16x16x32_f16(
            ah[mf], bh[nf], facc[mf][nf], 0, 0, 0);
  }

  // + bias, store
  #pragma unroll
  for (int mf = 0; mf < 4; ++mf)
    #pragma unroll
    for (int nf = 0; nf < 4; ++nf) {
      const int col = n0 + nf * 16 + (l & 15);
      #pragma unroll
      for (int j = 0; j < 4; ++j) {
        const int row = w * 64 + mf * 16 + (l >> 4) * 4 + j;
        out[(size_t)row * OUT_F + col] = facc[mf][nf][j] + bs[nf];
      }
    }
}

extern "C" void kernel_launch(void* const* d_in, const int* in_sizes, int n_in,
                              void* d_out, int out_size, void* d_ws, size_t ws_size,
                              hipStream_t stream) {
  const float* x      = (const float*)d_in[0];
  const int*   qw     = (const int*)d_in[1];
  const float* scol   = (const float*)d_in[2];
  const float* wcache = (const float*)d_in[3];
  const int*   ind    = (const int*)d_in[4];
  const float* bias   = (const float*)d_in[5];
  float* out = (float*)d_out;

  signed char* qx = (signed char*)d_ws;                                   // 2 MB
  _Float16* act = (_Float16*)((char*)d_ws + (size_t)NROWS * IN_F);        // 256 KB
  float* xscale = (float*)((char*)d_ws + (size_t)NROWS * IN_F + (size_t)NROWS * FP_F * 2);

  quant_kernel<<<NROWS, 256, 0, stream>>>(x, ind, qx, act, xscale);
  gemm_kernel<<<OUT_F / BN, 512, 0, stream>>>(qx, qw, scol, wcache, bias, act, xscale, out);
}